// Round 1
// baseline (3615.950 us; speedup 1.0000x reference)
//
#include <hip/hip_runtime.h>
#include <hip/hip_bf16.h>

#define M_TOK 8192
#define K_DIM 1024
#define V_CLS 50257

typedef __attribute__((ext_vector_type(8))) short bf16x8;
typedef __attribute__((ext_vector_type(4))) float floatx4;

// ---- fp32 -> bf16 (round-nearest-even), 4 elems/thread/iter ----
__device__ __forceinline__ unsigned short f2bf_rne(float x) {
    unsigned int u = __builtin_bit_cast(unsigned int, x);
    u += 0x7fffu + ((u >> 16) & 1u);
    return (unsigned short)(u >> 16);
}

__global__ void cast_f32_bf16(const float4* __restrict__ src,
                              ushort4* __restrict__ dst, int n4) {
    int i = blockIdx.x * blockDim.x + threadIdx.x;
    int stride = gridDim.x * blockDim.x;
    for (; i < n4; i += stride) {
        float4 v = src[i];
        ushort4 o;
        o.x = f2bf_rne(v.x);
        o.y = f2bf_rne(v.y);
        o.z = f2bf_rne(v.z);
        o.w = f2bf_rne(v.w);
        dst[i] = o;
    }
}

// ---- bf16 GEMM, C = A(M,K) * B(V,K)^T, fp32 out. m97 structure:
// 128x128 tile, BK=64, 4 waves, 4x4 16x16x32 MFMAs/wave, global_load_lds w=16.
__global__ __launch_bounds__(256) void gemm_bt(
        const unsigned short* __restrict__ A,   // [M,K] bf16 bits
        const unsigned short* __restrict__ B,   // [V,K] bf16 bits
        float* __restrict__ C) {                // [M,V] fp32
    __shared__ unsigned short As[128 * 64];
    __shared__ unsigned short Bs[128 * 64];

    const int bid = blockIdx.x;
    const int mt = bid % (M_TOK / 128);   // m-major: 64 consecutive blocks share a W tile
    const int nt = bid / (M_TOK / 128);
    const int tid = threadIdx.x;
    const int lane = tid & 63;
    const int wave = tid >> 6;
    const int wm = (wave >> 1) * 64;
    const int wn = (wave & 1) * 64;

    const int rowA0 = mt * 128;
    const int rowB0 = nt * 128;

    // staging coords: thread t loads 16B (8 bf16); 8 threads/row, 32 rows/instr
    const int sr = tid >> 3;          // 0..31
    const int sc = (tid & 7) * 8;     // 0..56

    floatx4 acc[4][4] = {};

    for (int k0 = 0; k0 < K_DIM; k0 += 64) {
#pragma unroll
        for (int i = 0; i < 4; ++i) {
            const unsigned short* gp =
                A + ((long long)(rowA0 + i * 32 + sr) * K_DIM + k0 + sc);
            __builtin_amdgcn_global_load_lds(
                (const __attribute__((address_space(1))) void*)gp,
                (__attribute__((address_space(3))) void*)&As[i * 2048 + tid * 8],
                16, 0, 0);
        }
#pragma unroll
        for (int i = 0; i < 4; ++i) {
            int r = rowB0 + i * 32 + sr;
            if (r > V_CLS - 1) r = V_CLS - 1;   // clamp: dup row, stores guarded
            const unsigned short* gp = B + ((long long)r * K_DIM + k0 + sc);
            __builtin_amdgcn_global_load_lds(
                (const __attribute__((address_space(1))) void*)gp,
                (__attribute__((address_space(3))) void*)&Bs[i * 2048 + tid * 8],
                16, 0, 0);
        }
        __syncthreads();

#pragma unroll
        for (int ks = 0; ks < 2; ++ks) {
            bf16x8 aF[4], bF[4];
            const int kof = ks * 32 + (lane >> 4) * 8;
            const int rA = wm + (lane & 15);
            const int rB = wn + (lane & 15);
#pragma unroll
            for (int i = 0; i < 4; ++i)
                aF[i] = *(const bf16x8*)&As[(rA + i * 16) * 64 + kof];
#pragma unroll
            for (int j = 0; j < 4; ++j)
                bF[j] = *(const bf16x8*)&Bs[(rB + j * 16) * 64 + kof];
#pragma unroll
            for (int i = 0; i < 4; ++i)
#pragma unroll
                for (int j = 0; j < 4; ++j)
                    acc[i][j] = __builtin_amdgcn_mfma_f32_16x16x32_bf16(
                        aF[i], bF[j], acc[i][j], 0, 0, 0);
        }
        __syncthreads();
    }

    // epilogue: C/D layout col=lane&15, row=(lane>>4)*4+reg  [m89-verified]
    const int col0 = rowB0 + wn + (lane & 15);
    const int row0 = rowA0 + wm + ((lane >> 4) * 4);
#pragma unroll
    for (int i = 0; i < 4; ++i) {
#pragma unroll
        for (int j = 0; j < 4; ++j) {
            const int col = col0 + j * 16;
            if (col < V_CLS) {
#pragma unroll
                for (int r = 0; r < 4; ++r) {
                    long long idx = (long long)(row0 + i * 16 + r) * V_CLS + col;
                    C[idx] = acc[i][j][r];
                }
            }
        }
    }
}

// ---- per-row online logsumexp + NLL ----
__global__ __launch_bounds__(256) void row_lse_nll(
        const float* __restrict__ logits, const int* __restrict__ targets,
        float* __restrict__ nll) {
    const int n = blockIdx.x;
    const long long base = (long long)n * V_CLS;
    const int tid = threadIdx.x;

    float m = -1e30f, s = 0.0f;
    for (int v = tid; v < V_CLS; v += 256) {
        float x = logits[base + v];
        float nm = fmaxf(m, x);
        s = s * __expf(m - nm) + __expf(x - nm);
        m = nm;
    }

    __shared__ float sm[256], ss[256];
    sm[tid] = m;
    ss[tid] = s;
    __syncthreads();
    for (int off = 128; off > 0; off >>= 1) {
        if (tid < off) {
            float m2 = sm[tid + off], s2 = ss[tid + off];
            float nm = fmaxf(sm[tid], m2);
            ss[tid] = ss[tid] * __expf(sm[tid] - nm) + s2 * __expf(m2 - nm);
            sm[tid] = nm;
        }
        __syncthreads();
    }
    if (tid == 0) {
        int t = targets[n];
        float lse = sm[0] + __logf(ss[0]);
        nll[n] = lse - logits[base + t];
    }
}

__global__ __launch_bounds__(256) void loss_reduce(
        const float* __restrict__ nll, float* __restrict__ out) {
    __shared__ float sh[256];
    const int tid = threadIdx.x;
    float s = 0.0f;
    for (int i = tid; i < M_TOK; i += 256) s += nll[i];
    sh[tid] = s;
    __syncthreads();
    for (int off = 128; off > 0; off >>= 1) {
        if (tid < off) sh[tid] += sh[tid + off];
        __syncthreads();
    }
    if (tid == 0) out[(long long)M_TOK * V_CLS] = sh[0] / (float)M_TOK;
}

extern "C" void kernel_launch(void* const* d_in, const int* in_sizes, int n_in,
                              void* d_out, int out_size, void* d_ws, size_t ws_size,
                              hipStream_t stream) {
    const float* inputs = (const float*)d_in[0];
    const int* targets = (const int*)d_in[1];   // harness lowers ints to int32
    const float* W = (const float*)d_in[2];
    float* out = (float*)d_out;

    unsigned short* A_bf = (unsigned short*)d_ws;                     // 16.78 MB
    unsigned short* W_bf = A_bf + (size_t)M_TOK * K_DIM;              // 102.93 MB
    float* nll = (float*)(W_bf + (size_t)V_CLS * K_DIM);              // 32 KB

    const int nA4 = M_TOK * K_DIM / 4;
    const int nW4 = V_CLS * K_DIM / 4;
    cast_f32_bf16<<<2048, 256, 0, stream>>>((const float4*)inputs, (ushort4*)A_bf, nA4);
    cast_f32_bf16<<<8192, 256, 0, stream>>>((const float4*)W, (ushort4*)W_bf, nW4);

    const int grid = (M_TOK / 128) * ((V_CLS + 127) / 128);  // 64 * 393
    gemm_bt<<<grid, 256, 0, stream>>>(A_bf, W_bf, out);

    row_lse_nll<<<M_TOK, 256, 0, stream>>>(out, targets, nll);
    loss_reduce<<<1, 256, 0, stream>>>(nll, out);
}